// Round 1
// baseline (399.762 us; speedup 1.0000x reference)
//
#include <hip/hip_runtime.h>

#define D 64

// Kernel 1: per-edge scatter-add of feature rows into out (used as h accumulator).
// One edge per wave: lane i handles feature dim i. Gather read is a coalesced
// 256B row; atomics are contiguous 256B region at dst row.
__global__ void gcn_scatter_kernel(const float* __restrict__ feature,
                                   const int* __restrict__ src,
                                   const int* __restrict__ dst,
                                   float* __restrict__ out,
                                   int n_edges) {
    int e = blockIdx.x * 4 + (threadIdx.x >> 6);
    int lane = threadIdx.x & 63;
    if (e < n_edges) {
        int s = src[e];
        int d = dst[e];
        atomicAdd(&out[d * D + lane], feature[s * D + lane]);
    }
}

// Kernel 2: in-place linear. Each wave owns one node row:
// load h[n][lane] -> shuffle-broadcast dot with W -> out[n][lane] = b[lane] + dot.
// Safe in-place: only this wave touches row n, and the load precedes the store.
__global__ void gcn_linear_kernel(float* __restrict__ out,
                                  const float* __restrict__ W,
                                  const float* __restrict__ b,
                                  int n_nodes) {
    // Wt[k*65 + o] = W[o*64 + k]; stride-65 padding => conflict-free writes & reads.
    __shared__ float Wt[64 * 65];
    int tid = threadIdx.x;
    for (int i = tid; i < 64 * 64; i += 256) {
        int o = i >> 6;
        int k = i & 63;
        Wt[k * 65 + o] = W[i];
    }
    __syncthreads();

    int wave = tid >> 6;
    int lane = tid & 63;
    int n = blockIdx.x * 4 + wave;
    if (n >= n_nodes) return;

    float val = out[n * D + lane];  // h[n][lane]
    float acc = b[lane];
#pragma unroll
    for (int k = 0; k < 64; ++k) {
        float hk = __shfl(val, k, 64);
        acc += hk * Wt[k * 65 + lane];
    }
    out[n * D + lane] = acc;
}

extern "C" void kernel_launch(void* const* d_in, const int* in_sizes, int n_in,
                              void* d_out, int out_size, void* d_ws, size_t ws_size,
                              hipStream_t stream) {
    const float* feature = (const float*)d_in[0];
    const int* src       = (const int*)d_in[1];
    const int* dst       = (const int*)d_in[2];
    const float* W       = (const float*)d_in[3];
    const float* b       = (const float*)d_in[4];
    float* out           = (float*)d_out;

    int n_edges = in_sizes[1];
    int n_nodes = in_sizes[0] / D;

    // d_out is poisoned 0xAA before every launch -> zero it (capture-safe).
    hipMemsetAsync(d_out, 0, (size_t)out_size * sizeof(float), stream);

    // Aggregate: h[dst] += feature[src]
    int scatter_blocks = (n_edges + 3) / 4;
    gcn_scatter_kernel<<<scatter_blocks, 256, 0, stream>>>(feature, src, dst, out, n_edges);

    // Linear in-place: out = h @ W.T + b
    int linear_blocks = (n_nodes + 3) / 4;
    gcn_linear_kernel<<<linear_blocks, 256, 0, stream>>>(out, W, b, n_nodes);
}

// Round 2
// 330.727 us; speedup vs baseline: 1.2087x; 1.2087x over previous
//
#include <hip/hip_runtime.h>

#define D 64
#define SCAN_CHUNK 1024   // counts handled per scan block (256 thr x 4)

// ---------------- CSR build ----------------

__global__ void hist_kernel(const int* __restrict__ dst, int* __restrict__ counts, int n_edges) {
    int e = blockIdx.x * blockDim.x + threadIdx.x;
    if (e < n_edges) atomicAdd(&counts[dst[e]], 1);
}

// per-block sums of counts (1024 counts per block)
__global__ void reduce_kernel(const int* __restrict__ counts, int* __restrict__ partials, int n_nodes) {
    __shared__ int wsums[4];
    int tid = threadIdx.x;
    int base = blockIdx.x * SCAN_CHUNK + tid * 4;
    int s = 0;
#pragma unroll
    for (int i = 0; i < 4; ++i) {
        int idx = base + i;
        if (idx < n_nodes) s += counts[idx];
    }
    for (int o = 32; o > 0; o >>= 1) s += __shfl_down(s, o, 64);
    int lane = tid & 63, wave = tid >> 6;
    if (lane == 0) wsums[wave] = s;
    __syncthreads();
    if (tid == 0) partials[blockIdx.x] = wsums[0] + wsums[1] + wsums[2] + wsums[3];
}

// exclusive scan of <=64 partials, single wave
__global__ void scan_partials_kernel(const int* __restrict__ partials, int* __restrict__ pscan, int nblk) {
    int lane = threadIdx.x;
    int v = (lane < nblk) ? partials[lane] : 0;
    int orig = v;
    for (int o = 1; o < 64; o <<= 1) {
        int y = __shfl_up(v, o, 64);
        if (lane >= o) v += y;
    }
    if (lane < nblk) pscan[lane] = v - orig;
}

// exclusive scan of counts -> offsets (and a mutable copy: cursors)
__global__ void scan_kernel(const int* __restrict__ counts, const int* __restrict__ pscan,
                            int* __restrict__ offsets, int* __restrict__ cursors, int n_nodes) {
    __shared__ int wsums[4];
    int tid = threadIdx.x;
    int base = blockIdx.x * SCAN_CHUNK + tid * 4;
    int c[4];
    int tsum = 0;
#pragma unroll
    for (int i = 0; i < 4; ++i) {
        int idx = base + i;
        c[i] = (idx < n_nodes) ? counts[idx] : 0;
        tsum += c[i];
    }
    int lane = tid & 63, wave = tid >> 6;
    int x = tsum;
    for (int o = 1; o < 64; o <<= 1) {
        int y = __shfl_up(x, o, 64);
        if (lane >= o) x += y;
    }
    if (lane == 63) wsums[wave] = x;
    __syncthreads();
    int wpre = 0;
    for (int w = 0; w < wave; ++w) wpre += wsums[w];
    int excl = (x - tsum) + wpre + pscan[blockIdx.x];
#pragma unroll
    for (int i = 0; i < 4; ++i) {
        int idx = base + i;
        if (idx < n_nodes) { offsets[idx] = excl; cursors[idx] = excl; }
        excl += c[i];
    }
}

__global__ void fill_kernel(const int* __restrict__ src, const int* __restrict__ dst,
                            int* __restrict__ cursors, int* __restrict__ elist, int n_edges) {
    int e = blockIdx.x * blockDim.x + threadIdx.x;
    if (e < n_edges) {
        int pos = atomicAdd(&cursors[dst[e]], 1);
        elist[pos] = src[e];
    }
}

// ---------------- fused aggregate + linear ----------------
// One wave per node (grid-stride): register-accumulate gathered rows, then
// out[n][lane] = b[lane] + sum_k h[k] * W[lane][k] via shuffle-broadcast.
__global__ void agg_linear_kernel(const float* __restrict__ feature,
                                  const int* __restrict__ elist,
                                  const int* __restrict__ offsets,
                                  const int* __restrict__ counts,
                                  const float* __restrict__ W,
                                  const float* __restrict__ b,
                                  float* __restrict__ out,
                                  int n_nodes, int total_waves) {
    __shared__ float Wt[64 * 65];   // Wt[k*65+o] = W[o][k]; stride 65 => conflict-free
    int tid = threadIdx.x;
    for (int i = tid; i < 64 * 64; i += 256) {
        int o = i >> 6, k = i & 63;
        Wt[k * 65 + o] = W[i];
    }
    __syncthreads();

    int lane = tid & 63;
    int waveId = (blockIdx.x * 256 + tid) >> 6;
    float bias = b[lane];

    for (int n = waveId; n < n_nodes; n += total_waves) {
        int off = offsets[n];
        int deg = counts[n];
        float acc = 0.f;
        int j = 0;
        for (; j + 4 <= deg; j += 4) {
            int s0 = elist[off + j + 0];
            int s1 = elist[off + j + 1];
            int s2 = elist[off + j + 2];
            int s3 = elist[off + j + 3];
            float f0 = feature[s0 * D + lane];
            float f1 = feature[s1 * D + lane];
            float f2 = feature[s2 * D + lane];
            float f3 = feature[s3 * D + lane];
            acc += f0 + f1 + f2 + f3;
        }
        for (; j < deg; ++j) acc += feature[elist[off + j] * D + lane];

        float r = bias;
#pragma unroll
        for (int k = 0; k < 64; ++k) {
            r += __shfl(acc, k, 64) * Wt[k * 65 + lane];
        }
        out[n * D + lane] = r;
    }
}

// ---------------- fallback (round-1 path) ----------------

__global__ void gcn_scatter_kernel(const float* __restrict__ feature,
                                   const int* __restrict__ src,
                                   const int* __restrict__ dst,
                                   float* __restrict__ out,
                                   int n_edges) {
    int e = blockIdx.x * 4 + (threadIdx.x >> 6);
    int lane = threadIdx.x & 63;
    if (e < n_edges) {
        atomicAdd(&out[dst[e] * D + lane], feature[src[e] * D + lane]);
    }
}

__global__ void gcn_linear_kernel(float* __restrict__ out,
                                  const float* __restrict__ W,
                                  const float* __restrict__ b,
                                  int n_nodes) {
    __shared__ float Wt[64 * 65];
    int tid = threadIdx.x;
    for (int i = tid; i < 64 * 64; i += 256) {
        int o = i >> 6, k = i & 63;
        Wt[k * 65 + o] = W[i];
    }
    __syncthreads();
    int lane = tid & 63;
    int n = blockIdx.x * 4 + (tid >> 6);
    if (n >= n_nodes) return;
    float val = out[n * D + lane];
    float acc = b[lane];
#pragma unroll
    for (int k = 0; k < 64; ++k) acc += __shfl(val, k, 64) * Wt[k * 65 + lane];
    out[n * D + lane] = acc;
}

extern "C" void kernel_launch(void* const* d_in, const int* in_sizes, int n_in,
                              void* d_out, int out_size, void* d_ws, size_t ws_size,
                              hipStream_t stream) {
    const float* feature = (const float*)d_in[0];
    const int* src       = (const int*)d_in[1];
    const int* dst       = (const int*)d_in[2];
    const float* W       = (const float*)d_in[3];
    const float* b       = (const float*)d_in[4];
    float* out           = (float*)d_out;

    int n_edges = in_sizes[1];
    int n_nodes = in_sizes[0] / D;

    // workspace layout (ints): counts[N] | offsets[N] | cursors[N] | partials[64] | pscan[64] | elist[E]
    size_t need = ((size_t)3 * n_nodes + 128 + (size_t)n_edges) * sizeof(int);

    if (ws_size < need) {
        // fallback: atomic scatter path
        hipMemsetAsync(d_out, 0, (size_t)out_size * sizeof(float), stream);
        gcn_scatter_kernel<<<(n_edges + 3) / 4, 256, 0, stream>>>(feature, src, dst, out, n_edges);
        gcn_linear_kernel<<<(n_nodes + 3) / 4, 256, 0, stream>>>(out, W, b, n_nodes);
        return;
    }

    int* counts   = (int*)d_ws;
    int* offsets  = counts + n_nodes;
    int* cursors  = offsets + n_nodes;
    int* partials = cursors + n_nodes;
    int* pscan    = partials + 64;
    int* elist    = pscan + 64;

    int nblk = (n_nodes + SCAN_CHUNK - 1) / SCAN_CHUNK;   // 49 for N=50000

    hipMemsetAsync(counts, 0, (size_t)n_nodes * sizeof(int), stream);
    hist_kernel<<<(n_edges + 255) / 256, 256, 0, stream>>>(dst, counts, n_edges);
    reduce_kernel<<<nblk, 256, 0, stream>>>(counts, partials, n_nodes);
    scan_partials_kernel<<<1, 64, 0, stream>>>(partials, pscan, nblk);
    scan_kernel<<<nblk, 256, 0, stream>>>(counts, pscan, offsets, cursors, n_nodes);
    fill_kernel<<<(n_edges + 255) / 256, 256, 0, stream>>>(src, dst, cursors, elist, n_edges);

    int agg_blocks = 3125;                     // 12500 waves, ~4 nodes/wave
    int total_waves = agg_blocks * 4;
    agg_linear_kernel<<<agg_blocks, 256, 0, stream>>>(feature, elist, offsets, counts,
                                                      W, b, out, n_nodes, total_waves);
}

// Round 3
// 297.177 us; speedup vs baseline: 1.3452x; 1.1129x over previous
//
#include <hip/hip_runtime.h>

#define D 64
#define SCAN_CHUNK 1024   // counts handled per scan block (256 thr x 4)
#define PAD 16            // one counter per 64B line -> no same-line atomic serialization

// ---------------- CSR build (padded counters) ----------------

__global__ void hist_kernel(const int* __restrict__ dst, int* __restrict__ counts,
                            int n_edges, int pad) {
    int e = blockIdx.x * blockDim.x + threadIdx.x;
    if (e < n_edges) atomicAdd(&counts[dst[e] * pad], 1);
}

// per-block sums of counts (1024 counts per block)
__global__ void reduce_kernel(const int* __restrict__ counts, int* __restrict__ partials,
                              int n_nodes, int pad) {
    __shared__ int wsums[4];
    int tid = threadIdx.x;
    int base = blockIdx.x * SCAN_CHUNK + tid * 4;
    int s = 0;
#pragma unroll
    for (int i = 0; i < 4; ++i) {
        int idx = base + i;
        if (idx < n_nodes) s += counts[idx * pad];
    }
    for (int o = 32; o > 0; o >>= 1) s += __shfl_down(s, o, 64);
    int lane = tid & 63, wave = tid >> 6;
    if (lane == 0) wsums[wave] = s;
    __syncthreads();
    if (tid == 0) partials[blockIdx.x] = wsums[0] + wsums[1] + wsums[2] + wsums[3];
}

// exclusive scan of <=64 partials, single wave
__global__ void scan_partials_kernel(const int* __restrict__ partials, int* __restrict__ pscan, int nblk) {
    int lane = threadIdx.x;
    int v = (lane < nblk) ? partials[lane] : 0;
    int orig = v;
    for (int o = 1; o < 64; o <<= 1) {
        int y = __shfl_up(v, o, 64);
        if (lane >= o) v += y;
    }
    if (lane < nblk) pscan[lane] = v - orig;
}

// exclusive scan of counts -> offsets (dense) and cursors (padded, mutable)
__global__ void scan_kernel(const int* __restrict__ counts, const int* __restrict__ pscan,
                            int* __restrict__ offsets, int* __restrict__ cursors,
                            int n_nodes, int pad) {
    __shared__ int wsums[4];
    int tid = threadIdx.x;
    int base = blockIdx.x * SCAN_CHUNK + tid * 4;
    int c[4];
    int tsum = 0;
#pragma unroll
    for (int i = 0; i < 4; ++i) {
        int idx = base + i;
        c[i] = (idx < n_nodes) ? counts[idx * pad] : 0;
        tsum += c[i];
    }
    int lane = tid & 63, wave = tid >> 6;
    int x = tsum;
    for (int o = 1; o < 64; o <<= 1) {
        int y = __shfl_up(x, o, 64);
        if (lane >= o) x += y;
    }
    if (lane == 63) wsums[wave] = x;
    __syncthreads();
    int wpre = 0;
    for (int w = 0; w < wave; ++w) wpre += wsums[w];
    int excl = (x - tsum) + wpre + pscan[blockIdx.x];
#pragma unroll
    for (int i = 0; i < 4; ++i) {
        int idx = base + i;
        if (idx < n_nodes) { offsets[idx] = excl; cursors[idx * pad] = excl; }
        excl += c[i];
    }
}

__global__ void fill_kernel(const int* __restrict__ src, const int* __restrict__ dst,
                            int* __restrict__ cursors, int* __restrict__ elist,
                            int n_edges, int pad) {
    int e = blockIdx.x * blockDim.x + threadIdx.x;
    if (e < n_edges) {
        int pos = atomicAdd(&cursors[dst[e] * pad], 1);
        elist[pos] = src[e];
    }
}

// ---------------- transform first: XW = feature @ W.T ----------------
__global__ void xw_kernel(const float* __restrict__ feature,
                          const float* __restrict__ W,
                          float* __restrict__ XW,
                          int n_nodes, int total_waves) {
    __shared__ float Wt[64 * 65];   // Wt[k*65+o] = W[o][k]
    int tid = threadIdx.x;
    for (int i = tid; i < 64 * 64; i += 256) {
        int o = i >> 6, k = i & 63;
        Wt[k * 65 + o] = W[i];
    }
    __syncthreads();
    int lane = tid & 63;
    int waveId = (blockIdx.x * 256 + tid) >> 6;
    for (int n = waveId; n < n_nodes; n += total_waves) {
        float val = feature[n * D + lane];
        float acc = 0.f;
#pragma unroll
        for (int k = 0; k < 64; ++k) acc += __shfl(val, k, 64) * Wt[k * 65 + lane];
        XW[n * D + lane] = acc;
    }
}

// ---------------- gather-sum: out[n] = b + sum XW[neighbors] ----------------
// One wave per node. Neighbor indices loaded coalesced (one per lane), then
// shuffle-broadcast; 4-wide unrolled gather with 2 accumulators. No LDS.
__global__ void agg_kernel(const float* __restrict__ XW,
                           const int* __restrict__ elist,
                           const int* __restrict__ offsets,
                           const int* __restrict__ counts,
                           const float* __restrict__ b,
                           float* __restrict__ out,
                           int n_nodes, int pad) {
    int gid = blockIdx.x * blockDim.x + threadIdx.x;
    int n = gid >> 6;
    int lane = threadIdx.x & 63;
    if (n >= n_nodes) return;

    int off = offsets[n];
    int deg = counts[n * pad];

    float acc0 = 0.f, acc1 = 0.f;
    for (int base = 0; base < deg; base += 64) {
        int m = deg - base; if (m > 64) m = 64;
        int eidx = (lane < m) ? elist[off + base + lane] : 0;
        int j = 0;
        for (; j + 4 <= m; j += 4) {
            int s0 = __shfl(eidx, j + 0, 64);
            int s1 = __shfl(eidx, j + 1, 64);
            int s2 = __shfl(eidx, j + 2, 64);
            int s3 = __shfl(eidx, j + 3, 64);
            float f0 = XW[s0 * D + lane];
            float f1 = XW[s1 * D + lane];
            float f2 = XW[s2 * D + lane];
            float f3 = XW[s3 * D + lane];
            acc0 += f0 + f1;
            acc1 += f2 + f3;
        }
        for (; j < m; ++j) {
            int s = __shfl(eidx, j, 64);
            acc0 += XW[s * D + lane];
        }
    }
    out[n * D + lane] = b[lane] + acc0 + acc1;
}

// ---------------- fallback path (round-2, proven) ----------------

__global__ void agg_linear_kernel(const float* __restrict__ feature,
                                  const int* __restrict__ elist,
                                  const int* __restrict__ offsets,
                                  const int* __restrict__ counts,
                                  const float* __restrict__ W,
                                  const float* __restrict__ b,
                                  float* __restrict__ out,
                                  int n_nodes, int total_waves) {
    __shared__ float Wt[64 * 65];
    int tid = threadIdx.x;
    for (int i = tid; i < 64 * 64; i += 256) {
        int o = i >> 6, k = i & 63;
        Wt[k * 65 + o] = W[i];
    }
    __syncthreads();
    int lane = tid & 63;
    int waveId = (blockIdx.x * 256 + tid) >> 6;
    float bias = b[lane];
    for (int n = waveId; n < n_nodes; n += total_waves) {
        int off = offsets[n];
        int deg = counts[n];
        float acc = 0.f;
        int j = 0;
        for (; j + 4 <= deg; j += 4) {
            int s0 = elist[off + j + 0];
            int s1 = elist[off + j + 1];
            int s2 = elist[off + j + 2];
            int s3 = elist[off + j + 3];
            acc += feature[s0 * D + lane] + feature[s1 * D + lane]
                 + feature[s2 * D + lane] + feature[s3 * D + lane];
        }
        for (; j < deg; ++j) acc += feature[elist[off + j] * D + lane];
        float r = bias;
#pragma unroll
        for (int k = 0; k < 64; ++k) r += __shfl(acc, k, 64) * Wt[k * 65 + lane];
        out[n * D + lane] = r;
    }
}

__global__ void gcn_scatter_kernel(const float* __restrict__ feature,
                                   const int* __restrict__ src,
                                   const int* __restrict__ dst,
                                   float* __restrict__ out,
                                   int n_edges) {
    int e = blockIdx.x * 4 + (threadIdx.x >> 6);
    int lane = threadIdx.x & 63;
    if (e < n_edges) atomicAdd(&out[dst[e] * D + lane], feature[src[e] * D + lane]);
}

__global__ void gcn_linear_kernel(float* __restrict__ out,
                                  const float* __restrict__ W,
                                  const float* __restrict__ b,
                                  int n_nodes) {
    __shared__ float Wt[64 * 65];
    int tid = threadIdx.x;
    for (int i = tid; i < 64 * 64; i += 256) {
        int o = i >> 6, k = i & 63;
        Wt[k * 65 + o] = W[i];
    }
    __syncthreads();
    int lane = tid & 63;
    int n = blockIdx.x * 4 + (tid >> 6);
    if (n >= n_nodes) return;
    float val = out[n * D + lane];
    float acc = b[lane];
#pragma unroll
    for (int k = 0; k < 64; ++k) acc += __shfl(val, k, 64) * Wt[k * 65 + lane];
    out[n * D + lane] = acc;
}

extern "C" void kernel_launch(void* const* d_in, const int* in_sizes, int n_in,
                              void* d_out, int out_size, void* d_ws, size_t ws_size,
                              hipStream_t stream) {
    const float* feature = (const float*)d_in[0];
    const int* src       = (const int*)d_in[1];
    const int* dst       = (const int*)d_in[2];
    const float* W       = (const float*)d_in[3];
    const float* b       = (const float*)d_in[4];
    float* out           = (float*)d_out;

    int n_edges = in_sizes[1];
    int n_nodes = in_sizes[0] / D;
    int nblk = (n_nodes + SCAN_CHUNK - 1) / SCAN_CHUNK;   // 49 for N=50000

    // Tier A layout (ints unless noted):
    // counts[N*PAD] | cursors[N*PAD] | offsets[N] | partials[64] | pscan[64] | elist[E] | XW[N*64 floats]
    size_t needA = ((size_t)2 * n_nodes * PAD + n_nodes + 128 + (size_t)n_edges
                    + (size_t)n_nodes * D) * sizeof(int);
    // Tier B (round-2): counts[N] | offsets[N] | cursors[N] | partials | pscan | elist[E]
    size_t needB = ((size_t)3 * n_nodes + 128 + (size_t)n_edges) * sizeof(int);

    if (ws_size >= needA) {
        int* counts   = (int*)d_ws;
        int* cursors  = counts + (size_t)n_nodes * PAD;
        int* offsets  = cursors + (size_t)n_nodes * PAD;
        int* partials = offsets + n_nodes;
        int* pscan    = partials + 64;
        int* elist    = pscan + 64;
        float* XW     = (float*)(elist + n_edges);

        hipMemsetAsync(counts, 0, (size_t)n_nodes * PAD * sizeof(int), stream);
        hist_kernel<<<(n_edges + 255) / 256, 256, 0, stream>>>(dst, counts, n_edges, PAD);
        xw_kernel<<<1024, 256, 0, stream>>>(feature, W, XW, n_nodes, 1024 * 4);
        reduce_kernel<<<nblk, 256, 0, stream>>>(counts, partials, n_nodes, PAD);
        scan_partials_kernel<<<1, 64, 0, stream>>>(partials, pscan, nblk);
        scan_kernel<<<nblk, 256, 0, stream>>>(counts, pscan, offsets, cursors, n_nodes, PAD);
        fill_kernel<<<(n_edges + 255) / 256, 256, 0, stream>>>(src, dst, cursors, elist, n_edges, PAD);

        int agg_blocks = (n_nodes * 64 + 255) / 256;   // one wave per node
        agg_kernel<<<agg_blocks, 256, 0, stream>>>(XW, elist, offsets, counts, b, out, n_nodes, PAD);
        return;
    }

    if (ws_size >= needB) {
        int* counts   = (int*)d_ws;
        int* offsets  = counts + n_nodes;
        int* cursors  = offsets + n_nodes;
        int* partials = cursors + n_nodes;
        int* pscan    = partials + 64;
        int* elist    = pscan + 64;

        hipMemsetAsync(counts, 0, (size_t)n_nodes * sizeof(int), stream);
        hist_kernel<<<(n_edges + 255) / 256, 256, 0, stream>>>(dst, counts, n_edges, 1);
        reduce_kernel<<<nblk, 256, 0, stream>>>(counts, partials, n_nodes, 1);
        scan_partials_kernel<<<1, 64, 0, stream>>>(partials, pscan, nblk);
        scan_kernel<<<nblk, 256, 0, stream>>>(counts, pscan, offsets, cursors, n_nodes, 1);
        fill_kernel<<<(n_edges + 255) / 256, 256, 0, stream>>>(src, dst, cursors, elist, n_edges, 1);
        agg_linear_kernel<<<3125, 256, 0, stream>>>(feature, elist, offsets, counts, W, b, out,
                                                    n_nodes, 3125 * 4);
        return;
    }

    // last-resort fallback (round-1)
    hipMemsetAsync(d_out, 0, (size_t)out_size * sizeof(float), stream);
    gcn_scatter_kernel<<<(n_edges + 3) / 4, 256, 0, stream>>>(feature, src, dst, out, n_edges);
    gcn_linear_kernel<<<(n_nodes + 3) / 4, 256, 0, stream>>>(out, W, b, n_nodes);
}